// Round 1
// 14089.906 us; speedup vs baseline: 1.1822x; 1.1822x over previous
//
#include <hip/hip_runtime.h>
#include <hip/hip_bf16.h>

// LSTM B=128,T=2048,H=256. Two-kernel plan (xp intermediate ELIMINATED):
//  prep: build (a) WXA combo table: bf16(Wih[:,x]+Wih[:,64+a]) for all 1024
//        (x,a) combos, [c][j][p] layout, 2 MB (L2-resident);
//        (b) packed per-(t,b) records {c=x*16+a | done<<16, rw fp32} 8B, 2 MB;
//        (c) obf bf16 B-fragments for Whh classes g,o (as before, 256 KB).
//  rec:  8 persistent WGs x 1024 thr; 16 batch rows/WG. Per step: 4 coalesced
//        8B gathers from WXA (L2) replace the old 512 MB xp stream; classes
//        i,f resident in regs, g kst0-1 + o kst0-5 in LDS (144.5 KB total),
//        g kst2-7 + o kst6-7 streamed from L2-resident obf. Records prefetched
//        one step ahead so the barrier's vmcnt(0) drain is free.

namespace {

constexpr int Tt   = 2048;
constexpr int Bb   = 128;
constexpr int Hh   = 256;
constexpr int NBat = 16;
constexpr int LDP  = 264;
constexpr int INED = 82;

constexpr size_t REC_OFF   = 0;
constexpr size_t REC_BYTES = (size_t)Bb * Tt * 8;        // 2 MB
constexpr size_t WXA_OFF   = REC_OFF + REC_BYTES;
constexpr size_t WXA_BYTES = (size_t)1024 * 1024 * 2;    // 2 MB
constexpr size_t OBF_OFF   = WXA_OFF + WXA_BYTES;
constexpr size_t OBF_BYTES = (size_t)2 * 16 * 8 * 64 * 16;  // 256 KB
constexpr size_t WS_NEED   = OBF_OFF + OBF_BYTES;

typedef __attribute__((ext_vector_type(8))) short short8;
typedef __attribute__((ext_vector_type(4))) float float4v;
typedef __attribute__((ext_vector_type(4))) unsigned short us4;

__device__ inline unsigned short bf16u(float f) {
  unsigned u = __float_as_uint(f);
  unsigned r = (u + 0x7FFFu + ((u >> 16) & 1u)) >> 16;  // RNE
  return (unsigned short)r;
}
__device__ inline float u2f(unsigned short u) {
  return __uint_as_float(((unsigned)u) << 16);
}
__device__ inline float sigf(float x) {
  float e = __builtin_amdgcn_exp2f(-1.4426950408889634f * x);
  return __builtin_amdgcn_rcpf(1.0f + e);
}
__device__ inline float tanhf_fast(float x) {
  float ax = __builtin_fabsf(x);
  float e  = __builtin_amdgcn_exp2f(-2.8853900817779268f * ax);
  float r  = (1.0f - e) * __builtin_amdgcn_rcpf(1.0f + e);
  return __builtin_copysignf(r, x);
}

// ---------------- prep: WXA table, packed records, Whh g/o bf16 fragments ----------------
__global__ __launch_bounds__(256) void prep_kernel(
    const int* __restrict__ xs, const int* __restrict__ pa,
    const float* __restrict__ prw, const float* __restrict__ pdn,
    const float* __restrict__ Wih, const float* __restrict__ Whh,
    unsigned char* __restrict__ ws)
{
  const int T1 = 1024 * 1024;      // WXA elements
  const int T2 = Bb * Tt;          // records
  const int T3 = 2 * 16 * 8 * 64;  // obf fragments
  int id = blockIdx.x * 256 + threadIdx.x;
  if (id < T1) {
    // WXA[c][j][p] = bf16(Wih[p*256+j][x] + Wih[p*256+j][64+a]), c = x*16+a
    int c = id >> 10, q = id & 1023, jj = q >> 2, p = q & 3;
    int x = c >> 4, a = c & 15;
    const float* row = Wih + (size_t)(p * 256 + jj) * INED;
    ((unsigned short*)(ws + WXA_OFF))[id] = bf16u(row[x] + row[64 + a]);
  } else if (id < T1 + T2) {
    int id2 = id - T1;
    int t = id2 & (Tt - 1), bg = id2 >> 11;
    const size_t src = (size_t)bg * Tt + t;
    int xv = xs[src], av = pa[src];
    float rw = prw[src];
    unsigned dnb = (pdn[src] != 0.0f) ? 1u : 0u;
    uint2 r;
    r.x = (unsigned)(xv * 16 + av) | (dnb << 16);
    r.y = __float_as_uint(rw);
    // rec[wg][t][b]
    ((uint2*)(ws + REC_OFF))[((size_t)(bg >> 4) * Tt + t) * NBat + (bg & 15)] = r;
  } else if (id < T1 + T2 + T3) {
    int id3 = id - T1 - T2;
    int l = id3 & 63, kst = (id3 >> 6) & 7, w = (id3 >> 9) & 15, c = id3 >> 13;
    int lm = l & 15, lq = l >> 4;
    int row = 512 + 256 * c + 16 * w + lm;  // class g rows [512,768), o rows [768,1024)
    int k0  = kst * 32 + lq * 8;
    const float* src = Whh + (size_t)row * Hh + k0;
    unsigned short* dst = (unsigned short*)(ws + OBF_OFF) + (size_t)id3 * 8;
    #pragma unroll
    for (int jj = 0; jj < 8; ++jj) dst[jj] = bf16u(src[jj]);
  }
}

// ---------------- recurrent kernel ----------------
__global__ __launch_bounds__(1024, 4) void lstm_rec(
    const float* __restrict__ hidden, const float* __restrict__ Whh,
    const float* __restrict__ Wih, const float* __restrict__ bih,
    const float* __restrict__ bhh,
    const unsigned char* __restrict__ ws, float* __restrict__ out)
{
  __shared__ alignas(16) short hbuf[2][NBat * LDP];     // 16.9 KB
  __shared__ alignas(16) short gfrag[2][16 * 64 * 8];   // class g, kst 0..1: 32 KB
  __shared__ alignas(16) short ofrag[6][16 * 64 * 8];   // class o, kst 0..5: 96 KB

  const unsigned short* obf = (const unsigned short*)(ws + OBF_OFF);
  const unsigned short* wxa = (const unsigned short*)(ws + WXA_OFF);
  const uint2* rec = (const uint2*)(ws + REC_OFF) + (size_t)blockIdx.x * Tt * NBat;

  const int tid = threadIdx.x;
  const int w   = tid >> 6;
  const int l   = tid & 63;
  const int lm  = l & 15;
  const int lq  = l >> 4;
  const int b0  = blockIdx.x * NBat;
  const int j   = 16 * w + lm;

  // resident B-frags: classes i (rows [0,256)) and f (rows [256,512))
  short8 bif[2][8];
  #pragma unroll
  for (int p = 0; p < 2; ++p) {
    const float* row = Whh + (size_t)(256 * p + j) * Hh;
    #pragma unroll
    for (int kst = 0; kst < 8; ++kst) {
      const int k0 = kst * 32 + lq * 8;
      short8 v;
      #pragma unroll
      for (int jj = 0; jj < 8; ++jj) v[jj] = (short)bf16u(row[k0 + jj]);
      bif[p][kst] = v;
    }
  }
  // class-g kst 0..1 into LDS
  {
    const float* row = Whh + (size_t)(512 + j) * Hh;
    #pragma unroll
    for (int kst = 0; kst < 2; ++kst) {
      const int k0 = kst * 32 + lq * 8;
      short8 v;
      #pragma unroll
      for (int jj = 0; jj < 8; ++jj) v[jj] = (short)bf16u(row[k0 + jj]);
      *(short8*)&gfrag[kst][(w * 64 + l) * 8] = v;
    }
  }
  // class-o kst 0..5 into LDS
  {
    const float* row = Whh + (size_t)(768 + j) * Hh;
    #pragma unroll
    for (int kst = 0; kst < 6; ++kst) {
      const int k0 = kst * 32 + lq * 8;
      short8 v;
      #pragma unroll
      for (int jj = 0; jj < 8; ++jj) v[jj] = (short)bf16u(row[k0 + jj]);
      *(short8*)&ofrag[kst][(w * 64 + l) * 8] = v;
    }
  }

  // per-lane input-projection coefficients (fp32): rw/dn columns + bias sum
  float w80p[4], w81p[4], bs[4];
  #pragma unroll
  for (int p = 0; p < 4; ++p) {
    const int g = p * 256 + j;
    w80p[p] = Wih[(size_t)g * INED + 80];
    w81p[p] = Wih[(size_t)g * INED + 81];
    bs[p]   = bih[g] + bhh[g];
  }

  // c-state init
  float cst[4];
  #pragma unroll
  for (int r = 0; r < 4; ++r)
    cst[r] = hidden[(size_t)(b0 + lq * 4 + r) * (2 * Hh) + Hh + j];

  // stage h(-1) into hbuf[1]
  for (int v = tid; v < NBat * Hh; v += 1024) {
    const int m = v >> 8, k = v & (Hh - 1);
    hbuf[1][m * LDP + k] = (short)bf16u(hidden[(size_t)(b0 + m) * (2 * Hh) + k]);
  }

  // record prefetch for t = 0
  uint2 rc[4];
  #pragma unroll
  for (int r = 0; r < 4; ++r) rc[r] = rec[lq * 4 + r];

  __syncthreads();

  for (int t = 0; t < Tt; ++t) {
    // input gathers for step t (consumed only in the epilogue -> L2 latency
    // hides under the MFMA loop): one 8B us4 per batch row, 4 lq-segments
    // of 128B per instruction.
    us4 gxa[4];
    #pragma unroll
    for (int r = 0; r < 4; ++r) {
      const unsigned c = rc[r].x & 0xFFFFu;
      gxa[r] = *(const us4*)(wxa + ((size_t)c << 10) + ((unsigned)j << 2));
    }
    // prefetch next step's records (arrives long before next-step epilogue;
    // the barrier's vmcnt(0) drain is a no-op by then)
    const int tn = (t + 1 < Tt) ? (t + 1) : t;
    uint2 rcN[4];
    #pragma unroll
    for (int r = 0; r < 4; ++r) rcN[r] = rec[(size_t)tn * NBat + lq * 4 + r];

    const short* hb = hbuf[(t + 1) & 1];
    float4v acc[4];
    #pragma unroll
    for (int p = 0; p < 4; ++p) acc[p] = float4v{0.f, 0.f, 0.f, 0.f};

    #pragma unroll
    for (int kst = 0; kst < 8; ++kst) {
      const short8 af = *(const short8*)(hb + lm * LDP + kst * 32 + lq * 8);
      acc[0] = __builtin_amdgcn_mfma_f32_16x16x32_bf16(af, bif[0][kst], acc[0], 0, 0, 0);
      acc[1] = __builtin_amdgcn_mfma_f32_16x16x32_bf16(af, bif[1][kst], acc[1], 0, 0, 0);
      short8 gf;
      if (kst < 2) gf = *(const short8*)&gfrag[kst][(w * 64 + l) * 8];
      else         gf = *(const short8*)(obf + (size_t)(((0 * 16 + w) * 8 + kst) * 64 + l) * 8);
      acc[2] = __builtin_amdgcn_mfma_f32_16x16x32_bf16(af, gf, acc[2], 0, 0, 0);
      short8 of;
      if (kst < 6) of = *(const short8*)&ofrag[kst][(w * 64 + l) * 8];
      else         of = *(const short8*)(obf + (size_t)(((16 + w) * 8 + kst) * 64 + l) * 8);
      acc[3] = __builtin_amdgcn_mfma_f32_16x16x32_bf16(af, of, acc[3], 0, 0, 0);
    }

    short* hw = hbuf[t & 1];
    #pragma unroll
    for (int r = 0; r < 4; ++r) {
      const float rw = __uint_as_float(rc[r].y);
      const float dn = (rc[r].x >> 16) ? 1.0f : 0.0f;
      const float iv = acc[0][r] + u2f(gxa[r][0]) + rw * w80p[0] + dn * w81p[0] + bs[0];
      const float fv = acc[1][r] + u2f(gxa[r][1]) + rw * w80p[1] + dn * w81p[1] + bs[1];
      const float gv = acc[2][r] + u2f(gxa[r][2]) + rw * w80p[2] + dn * w81p[2] + bs[2];
      const float ov = acc[3][r] + u2f(gxa[r][3]) + rw * w80p[3] + dn * w81p[3] + bs[3];
      const float c  = sigf(fv) * cst[r] + sigf(iv) * tanhf_fast(gv);
      cst[r] = c;
      const float hn = sigf(ov) * tanhf_fast(c);
      const int m = lq * 4 + r;
      out[((size_t)(b0 + m) * Tt + t) * Hh + j] = hn;
      hw[m * LDP + j] = (short)bf16u(hn);
    }
    #pragma unroll
    for (int r = 0; r < 4; ++r) rc[r] = rcN[r];
    __syncthreads();
  }

  // final_hidden = [hT | cT]; hT read back (bf16-rounded) from hbuf[1]
  const size_t base = (size_t)Bb * Tt * Hh;
  #pragma unroll
  for (int r = 0; r < 4; ++r) {
    const int m = lq * 4 + r;
    const float hT = u2f((unsigned short)hbuf[1][m * LDP + j]);
    out[base + (size_t)(b0 + m) * (2 * Hh) + j]      = hT;
    out[base + (size_t)(b0 + m) * (2 * Hh) + Hh + j] = cst[r];
  }
}

// ---------------- fallback (R1 kernel, known-correct, slow) ----------------
__global__ __launch_bounds__(1024, 4) void lstm_fused(
    const int* __restrict__ xs, const float* __restrict__ hidden,
    const int* __restrict__ pa, const float* __restrict__ prw,
    const float* __restrict__ pdn, const float* __restrict__ Wih,
    const float* __restrict__ Whh, const float* __restrict__ bih,
    const float* __restrict__ bhh, float* __restrict__ out)
{
  __shared__ alignas(16) short hbuf[2][NBat * LDP];
  const int tid = threadIdx.x;
  const int w = tid >> 6, l = tid & 63, lm = l & 15, lq = l >> 4;
  const int b0 = blockIdx.x * NBat;
  short8 bhhf[4][8];
  #pragma unroll
  for (int p = 0; p < 4; ++p) {
    const float* row = Whh + (size_t)(256 * p + 16 * w + lm) * Hh;
    #pragma unroll
    for (int kst = 0; kst < 8; ++kst) {
      short8 v;
      #pragma unroll
      for (int jj = 0; jj < 8; ++jj) v[jj] = (short)bf16u(row[kst * 32 + lq * 8 + jj]);
      bhhf[p][kst] = v;
    }
  }
  short8 bihf[4][3];
  #pragma unroll
  for (int p = 0; p < 4; ++p) {
    const float* row = Wih + (size_t)(256 * p + 16 * w + lm) * INED;
    #pragma unroll
    for (int ks = 0; ks < 3; ++ks) {
      short8 v;
      #pragma unroll
      for (int jj = 0; jj < 8; ++jj) {
        const int k = ks * 32 + lq * 8 + jj;
        v[jj] = (k < INED) ? (short)bf16u(row[k]) : (short)0;
      }
      bihf[p][ks] = v;
    }
  }
  const int j = 16 * w + lm;
  float bs[4];
  #pragma unroll
  for (int p = 0; p < 4; ++p) bs[p] = bih[256 * p + j] + bhh[256 * p + j];
  float cst[4], hlast[4];
  #pragma unroll
  for (int r = 0; r < 4; ++r) {
    cst[r] = hidden[(size_t)(b0 + lq * 4 + r) * (2 * Hh) + Hh + j];
    hlast[r] = 0.f;
  }
  for (int v = tid; v < NBat * Hh; v += 1024) {
    const int m = v >> 8, k = v & (Hh - 1);
    hbuf[1][m * LDP + k] = (short)bf16u(hidden[(size_t)(b0 + m) * (2 * Hh) + k]);
  }
  __syncthreads();
  const int xrow = (b0 + lm) * Tt;
  for (int t = 0; t < Tt; ++t) {
    const int xv = xs[xrow + t], av = pa[xrow + t];
    const unsigned short rwb = bf16u(prw[xrow + t]), dnb = bf16u(pdn[xrow + t]);
    const short* hb = hbuf[(t + 1) & 1];
    float4v acc[4];
    #pragma unroll
    for (int p = 0; p < 4; ++p) acc[p] = float4v{0.f, 0.f, 0.f, 0.f};
    #pragma unroll
    for (int kst = 0; kst < 8; ++kst) {
      const short8 af = *(const short8*)(hb + lm * LDP + kst * 32 + lq * 8);
      #pragma unroll
      for (int p = 0; p < 4; ++p)
        acc[p] = __builtin_amdgcn_mfma_f32_16x16x32_bf16(af, bhhf[p][kst], acc[p], 0, 0, 0);
    }
    #pragma unroll
    for (int ks = 0; ks < 3; ++ks) {
      short8 af;
      #pragma unroll
      for (int jj = 0; jj < 8; ++jj) {
        const int kk = ks * 32 + lq * 8 + jj;
        short v = ((kk == xv) || (kk == 64 + av)) ? (short)0x3F80 : (short)0;
        if (kk == 80) v = (short)rwb;
        if (kk == 81) v = (short)dnb;
        af[jj] = v;
      }
      #pragma unroll
      for (int p = 0; p < 4; ++p)
        acc[p] = __builtin_amdgcn_mfma_f32_16x16x32_bf16(af, bihf[p][ks], acc[p], 0, 0, 0);
    }
    short* hw = hbuf[t & 1];
    #pragma unroll
    for (int r = 0; r < 4; ++r) {
      const float iv = acc[0][r] + bs[0], fv = acc[1][r] + bs[1];
      const float gv = acc[2][r] + bs[2], ov = acc[3][r] + bs[3];
      const float c = sigf(fv) * cst[r] + sigf(iv) * tanhf_fast(gv);
      cst[r] = c;
      const float hn = sigf(ov) * tanhf_fast(c);
      hlast[r] = hn;
      const int m = lq * 4 + r;
      out[((size_t)(b0 + m) * Tt + t) * Hh + j] = hn;
      hw[m * LDP + j] = (short)bf16u(hn);
    }
    __syncthreads();
  }
  const size_t base = (size_t)Bb * Tt * Hh;
  #pragma unroll
  for (int r = 0; r < 4; ++r) {
    const int m = lq * 4 + r;
    out[base + (size_t)(b0 + m) * (2 * Hh) + j]      = hlast[r];
    out[base + (size_t)(b0 + m) * (2 * Hh) + Hh + j] = cst[r];
  }
}

}  // namespace

extern "C" void kernel_launch(void* const* d_in, const int* in_sizes, int n_in,
                              void* d_out, int out_size, void* d_ws, size_t ws_size,
                              hipStream_t stream) {
  const int*   xs     = (const int*)  d_in[0];
  const float* hidden = (const float*)d_in[1];
  const int*   pa     = (const int*)  d_in[2];
  const float* prw    = (const float*)d_in[3];
  const float* pdn    = (const float*)d_in[4];
  const float* Wih    = (const float*)d_in[5];
  const float* Whh    = (const float*)d_in[6];
  const float* bih    = (const float*)d_in[7];
  const float* bhh    = (const float*)d_in[8];
  float* out = (float*)d_out;

  if (ws_size >= WS_NEED) {
    unsigned char* ws = (unsigned char*)d_ws;
    const int prepN = (1024 * 1024 + Bb * Tt + 2 * 16 * 8 * 64 + 255) / 256;
    prep_kernel<<<dim3(prepN), dim3(256), 0, stream>>>(xs, pa, prw, pdn, Wih, Whh, ws);
    lstm_rec<<<dim3(8), dim3(1024), 0, stream>>>(hidden, Whh, Wih, bih, bhh, ws, out);
  } else {
    lstm_fused<<<dim3(8), dim3(1024), 0, stream>>>(
        xs, hidden, pa, prw, pdn, Wih, Whh, bih, bhh, out);
  }
}

// Round 2
// 8463.976 us; speedup vs baseline: 1.9681x; 1.6647x over previous
//
#include <hip/hip_runtime.h>
#include <hip/hip_bf16.h>

// LSTM B=128,T=2048,H=256. Two-kernel plan, R2: 32 recurrent WGs.
//  prep: (a) WXA combo table bf16(Wih[:,x]+Wih[:,64+a]) for 1024 (x,a) combos,
//        [c][j][p] layout, 2 MB; (b) packed per-(t,b) records
//        {c=x*16+a | done<<16, rw fp32} 8B, laid out [wg][t][4]; (c) obf bf16
//        B-fragments for Whh classes g,o (256 KB).
//  rec:  32 persistent WGs x 1024 thr; 4 batch rows/WG (4x the CUs of R1).
//        MFMA phase identical to R1 (A-frag rows 4..15 are zero padding, the
//        garbage outputs are discarded). MFMA results for the 4 valid rows are
//        redistributed through a 16 KB LDS gbuf so the gate/activation epilogue
//        is LANE-DENSE: each of 1024 threads owns one (row m, h-col j) pair ->
//        per-CU epilogue VALU work drops 4x vs R1. Barrier 2 is a raw
//        lgkmcnt-only s_barrier so out[] stores drain off the serial path.

namespace {

constexpr int Tt   = 2048;
constexpr int Bb   = 128;
constexpr int Hh   = 256;
constexpr int NBat = 16;   // fallback kernel rows/WG
constexpr int NBR  = 4;    // lstm_rec rows/WG (32 WGs)
constexpr int LDP  = 264;
constexpr int INED = 82;

constexpr size_t REC_OFF   = 0;
constexpr size_t REC_BYTES = (size_t)Bb * Tt * 8;        // 2 MB
constexpr size_t WXA_OFF   = REC_OFF + REC_BYTES;
constexpr size_t WXA_BYTES = (size_t)1024 * 1024 * 2;    // 2 MB
constexpr size_t OBF_OFF   = WXA_OFF + WXA_BYTES;
constexpr size_t OBF_BYTES = (size_t)2 * 16 * 8 * 64 * 16;  // 256 KB
constexpr size_t WS_NEED   = OBF_OFF + OBF_BYTES;

typedef __attribute__((ext_vector_type(8))) short short8;
typedef __attribute__((ext_vector_type(4))) float float4v;
typedef __attribute__((ext_vector_type(4))) unsigned short us4;

__device__ inline unsigned short bf16u(float f) {
  unsigned u = __float_as_uint(f);
  unsigned r = (u + 0x7FFFu + ((u >> 16) & 1u)) >> 16;  // RNE
  return (unsigned short)r;
}
__device__ inline float u2f(unsigned short u) {
  return __uint_as_float(((unsigned)u) << 16);
}
__device__ inline float sigf(float x) {
  float e = __builtin_amdgcn_exp2f(-1.4426950408889634f * x);
  return __builtin_amdgcn_rcpf(1.0f + e);
}
__device__ inline float tanhf_fast(float x) {
  float ax = __builtin_fabsf(x);
  float e  = __builtin_amdgcn_exp2f(-2.8853900817779268f * ax);
  float r  = (1.0f - e) * __builtin_amdgcn_rcpf(1.0f + e);
  return __builtin_copysignf(r, x);
}

// ---------------- prep: WXA table, packed records, Whh g/o bf16 fragments ----------------
__global__ __launch_bounds__(256) void prep_kernel(
    const int* __restrict__ xs, const int* __restrict__ pa,
    const float* __restrict__ prw, const float* __restrict__ pdn,
    const float* __restrict__ Wih, const float* __restrict__ Whh,
    unsigned char* __restrict__ ws)
{
  const int T1 = 1024 * 1024;      // WXA elements
  const int T2 = Bb * Tt;          // records
  const int T3 = 2 * 16 * 8 * 64;  // obf fragments
  int id = blockIdx.x * 256 + threadIdx.x;
  if (id < T1) {
    // WXA[c][j][p] = bf16(Wih[p*256+j][x] + Wih[p*256+j][64+a]), c = x*16+a
    int c = id >> 10, q = id & 1023, jj = q >> 2, p = q & 3;
    int x = c >> 4, a = c & 15;
    const float* row = Wih + (size_t)(p * 256 + jj) * INED;
    ((unsigned short*)(ws + WXA_OFF))[id] = bf16u(row[x] + row[64 + a]);
  } else if (id < T1 + T2) {
    int id2 = id - T1;
    int t = id2 & (Tt - 1), bg = id2 >> 11;
    const size_t src = (size_t)bg * Tt + t;
    int xv = xs[src], av = pa[src];
    float rw = prw[src];
    unsigned dnb = (pdn[src] != 0.0f) ? 1u : 0u;
    uint2 r;
    r.x = (unsigned)(xv * 16 + av) | (dnb << 16);
    r.y = __float_as_uint(rw);
    // rec[wg][t][b-in-wg], wg = bg/NBR
    ((uint2*)(ws + REC_OFF))[((size_t)(bg >> 2) * Tt + t) * NBR + (bg & 3)] = r;
  } else if (id < T1 + T2 + T3) {
    int id3 = id - T1 - T2;
    int l = id3 & 63, kst = (id3 >> 6) & 7, w = (id3 >> 9) & 15, c = id3 >> 13;
    int lm = l & 15, lq = l >> 4;
    int row = 512 + 256 * c + 16 * w + lm;  // class g rows [512,768), o rows [768,1024)
    int k0  = kst * 32 + lq * 8;
    const float* src = Whh + (size_t)row * Hh + k0;
    unsigned short* dst = (unsigned short*)(ws + OBF_OFF) + (size_t)id3 * 8;
    #pragma unroll
    for (int jj = 0; jj < 8; ++jj) dst[jj] = bf16u(src[jj]);
  }
}

// ---------------- recurrent kernel: 32 WGs x 4 rows, dense epilogue ----------------
__global__ __launch_bounds__(1024, 4) void lstm_rec(
    const float* __restrict__ hidden, const float* __restrict__ Whh,
    const float* __restrict__ Wih, const float* __restrict__ bih,
    const float* __restrict__ bhh,
    const unsigned char* __restrict__ ws, float* __restrict__ out)
{
  __shared__ alignas(16) short hbuf[16 * LDP];          // 8.4 KB; rows 0..3 valid, 4..15 zero pad
  __shared__ alignas(16) short gfrag[2][16 * 64 * 8];   // class g, kst 0..1: 32 KB
  __shared__ alignas(16) short ofrag[6][16 * 64 * 8];   // class o, kst 0..5: 96 KB
  __shared__ alignas(16) float gbuf[NBR * Hh * 4];      // [m][j][p] fp32 MFMA results: 16 KB

  const unsigned short* obf = (const unsigned short*)(ws + OBF_OFF);
  const unsigned short* wxa = (const unsigned short*)(ws + WXA_OFF);
  const uint2* rec = (const uint2*)(ws + REC_OFF) + (size_t)blockIdx.x * Tt * NBR;

  const int tid = threadIdx.x;
  const int w   = tid >> 6;
  const int l   = tid & 63;
  const int lm  = l & 15;
  const int lq  = l >> 4;
  const int b0  = blockIdx.x * NBR;
  const int j   = 16 * w + lm;      // MFMA-phase gate column

  // ---- MFMA-phase residency (identical to R1) ----
  short8 bif[2][8];
  #pragma unroll
  for (int p = 0; p < 2; ++p) {
    const float* row = Whh + (size_t)(256 * p + j) * Hh;
    #pragma unroll
    for (int kst = 0; kst < 8; ++kst) {
      const int k0 = kst * 32 + lq * 8;
      short8 v;
      #pragma unroll
      for (int jj = 0; jj < 8; ++jj) v[jj] = (short)bf16u(row[k0 + jj]);
      bif[p][kst] = v;
    }
  }
  {
    const float* row = Whh + (size_t)(512 + j) * Hh;
    #pragma unroll
    for (int kst = 0; kst < 2; ++kst) {
      const int k0 = kst * 32 + lq * 8;
      short8 v;
      #pragma unroll
      for (int jj = 0; jj < 8; ++jj) v[jj] = (short)bf16u(row[k0 + jj]);
      *(short8*)&gfrag[kst][(w * 64 + l) * 8] = v;
    }
  }
  {
    const float* row = Whh + (size_t)(768 + j) * Hh;
    #pragma unroll
    for (int kst = 0; kst < 6; ++kst) {
      const int k0 = kst * 32 + lq * 8;
      short8 v;
      #pragma unroll
      for (int jj = 0; jj < 8; ++jj) v[jj] = (short)bf16u(row[k0 + jj]);
      *(short8*)&ofrag[kst][(w * 64 + l) * 8] = v;
    }
  }

  // ---- epilogue ownership: thread owns (row mE, h-col jE) ----
  const int mE = tid >> 8;          // 0..3
  const int jE = tid & 255;         // 0..255
  float w80p[4], w81p[4], bsv[4];
  #pragma unroll
  for (int p = 0; p < 4; ++p) {
    const int g = p * 256 + jE;
    w80p[p] = Wih[(size_t)g * INED + 80];
    w81p[p] = Wih[(size_t)g * INED + 81];
    bsv[p]  = bih[g] + bhh[g];
  }
  float cst   = hidden[(size_t)(b0 + mE) * (2 * Hh) + Hh + jE];
  float hlast = 0.f;

  // hbuf: zero all 16 rows, then stage h(-1) into rows 0..3
  for (int v = tid; v < 16 * LDP; v += 1024) hbuf[v] = 0;
  __syncthreads();
  for (int v = tid; v < NBR * Hh; v += 1024) {
    const int mm = v >> 8, k = v & 255;
    hbuf[mm * LDP + k] = (short)bf16u(hidden[(size_t)(b0 + mm) * (2 * Hh) + k]);
  }

  uint2 rc = rec[mE];   // record for t = 0
  __syncthreads();

  for (int t = 0; t < Tt; ++t) {
    // early issues: WXA gather + next record (consumed in epilogue; L2
    // latency hides under the MFMA phase + bar1)
    const unsigned cc = rc.x & 0xFFFFu;
    const us4 gxa = *(const us4*)(wxa + ((size_t)cc << 10) + ((unsigned)jE << 2));
    const int tn = (t + 1 < Tt) ? (t + 1) : t;
    const uint2 rcN = rec[(size_t)tn * NBR + mE];

    float4v acc[4];
    #pragma unroll
    for (int p = 0; p < 4; ++p) acc[p] = float4v{0.f, 0.f, 0.f, 0.f};

    #pragma unroll
    for (int kst = 0; kst < 8; ++kst) {
      const short8 af = *(const short8*)(hbuf + lm * LDP + kst * 32 + lq * 8);
      acc[0] = __builtin_amdgcn_mfma_f32_16x16x32_bf16(af, bif[0][kst], acc[0], 0, 0, 0);
      acc[1] = __builtin_amdgcn_mfma_f32_16x16x32_bf16(af, bif[1][kst], acc[1], 0, 0, 0);
      short8 gf;
      if (kst < 2) gf = *(const short8*)&gfrag[kst][(w * 64 + l) * 8];
      else         gf = *(const short8*)(obf + (size_t)(((0 * 16 + w) * 8 + kst) * 64 + l) * 8);
      acc[2] = __builtin_amdgcn_mfma_f32_16x16x32_bf16(af, gf, acc[2], 0, 0, 0);
      short8 of;
      if (kst < 6) of = *(const short8*)&ofrag[kst][(w * 64 + l) * 8];
      else         of = *(const short8*)(obf + (size_t)(((16 + w) * 8 + kst) * 64 + l) * 8);
      acc[3] = __builtin_amdgcn_mfma_f32_16x16x32_bf16(af, of, acc[3], 0, 0, 0);
    }

    // redistribute valid rows (m = r, lanes lq==0) to gbuf[m][j][p]
    if (lq == 0) {
      #pragma unroll
      for (int r = 0; r < 4; ++r) {
        float4v v4;
        v4[0] = acc[0][r]; v4[1] = acc[1][r]; v4[2] = acc[2][r]; v4[3] = acc[3][r];
        *(float4v*)&gbuf[((r << 8) + j) << 2] = v4;
      }
    }
    __syncthreads();   // bar1

    // dense epilogue: 1 h-value per thread
    {
      const float4v g4 = *(const float4v*)&gbuf[((mE << 8) + jE) << 2];
      const float rw  = __uint_as_float(rc.y);
      const float dnw = (rc.x >> 16) ? 1.0f : 0.0f;
      const float iv = g4[0] + u2f(gxa[0]) + rw * w80p[0] + dnw * w81p[0] + bsv[0];
      const float fv = g4[1] + u2f(gxa[1]) + rw * w80p[1] + dnw * w81p[1] + bsv[1];
      const float gv = g4[2] + u2f(gxa[2]) + rw * w80p[2] + dnw * w81p[2] + bsv[2];
      const float ov = g4[3] + u2f(gxa[3]) + rw * w80p[3] + dnw * w81p[3] + bsv[3];
      const float c  = sigf(fv) * cst + sigf(iv) * tanhf_fast(gv);
      cst = c;
      const float hn = sigf(ov) * tanhf_fast(c);
      hlast = hn;
      out[((size_t)(b0 + mE) * Tt + t) * Hh + jE] = hn;
      hbuf[mE * LDP + jE] = (short)bf16u(hn);
    }
    rc = rcN;
    // bar2: LDS-only drain; out[] stores stay in flight (nothing reads them)
    asm volatile("s_waitcnt lgkmcnt(0)\n\ts_barrier" ::: "memory");
  }

  // final_hidden = [hT | cT], one element per thread
  const size_t fbase = (size_t)Bb * Tt * Hh;
  out[fbase + (size_t)(b0 + mE) * (2 * Hh) + jE]      = hlast;
  out[fbase + (size_t)(b0 + mE) * (2 * Hh) + Hh + jE] = cst;
}

// ---------------- fallback (R1 kernel, known-correct, slow) ----------------
__global__ __launch_bounds__(1024, 4) void lstm_fused(
    const int* __restrict__ xs, const float* __restrict__ hidden,
    const int* __restrict__ pa, const float* __restrict__ prw,
    const float* __restrict__ pdn, const float* __restrict__ Wih,
    const float* __restrict__ Whh, const float* __restrict__ bih,
    const float* __restrict__ bhh, float* __restrict__ out)
{
  __shared__ alignas(16) short hbuf[2][NBat * LDP];
  const int tid = threadIdx.x;
  const int w = tid >> 6, l = tid & 63, lm = l & 15, lq = l >> 4;
  const int b0 = blockIdx.x * NBat;
  short8 bhhf[4][8];
  #pragma unroll
  for (int p = 0; p < 4; ++p) {
    const float* row = Whh + (size_t)(256 * p + 16 * w + lm) * Hh;
    #pragma unroll
    for (int kst = 0; kst < 8; ++kst) {
      short8 v;
      #pragma unroll
      for (int jj = 0; jj < 8; ++jj) v[jj] = (short)bf16u(row[kst * 32 + lq * 8 + jj]);
      bhhf[p][kst] = v;
    }
  }
  short8 bihf[4][3];
  #pragma unroll
  for (int p = 0; p < 4; ++p) {
    const float* row = Wih + (size_t)(256 * p + 16 * w + lm) * INED;
    #pragma unroll
    for (int ks = 0; ks < 3; ++ks) {
      short8 v;
      #pragma unroll
      for (int jj = 0; jj < 8; ++jj) {
        const int k = ks * 32 + lq * 8 + jj;
        v[jj] = (k < INED) ? (short)bf16u(row[k]) : (short)0;
      }
      bihf[p][ks] = v;
    }
  }
  const int j = 16 * w + lm;
  float bs[4];
  #pragma unroll
  for (int p = 0; p < 4; ++p) bs[p] = bih[256 * p + j] + bhh[256 * p + j];
  float cst[4], hlast[4];
  #pragma unroll
  for (int r = 0; r < 4; ++r) {
    cst[r] = hidden[(size_t)(b0 + lq * 4 + r) * (2 * Hh) + Hh + j];
    hlast[r] = 0.f;
  }
  for (int v = tid; v < NBat * Hh; v += 1024) {
    const int m = v >> 8, k = v & (Hh - 1);
    hbuf[1][m * LDP + k] = (short)bf16u(hidden[(size_t)(b0 + m) * (2 * Hh) + k]);
  }
  __syncthreads();
  const int xrow = (b0 + lm) * Tt;
  for (int t = 0; t < Tt; ++t) {
    const int xv = xs[xrow + t], av = pa[xrow + t];
    const unsigned short rwb = bf16u(prw[xrow + t]), dnb = bf16u(pdn[xrow + t]);
    const short* hb = hbuf[(t + 1) & 1];
    float4v acc[4];
    #pragma unroll
    for (int p = 0; p < 4; ++p) acc[p] = float4v{0.f, 0.f, 0.f, 0.f};
    #pragma unroll
    for (int kst = 0; kst < 8; ++kst) {
      const short8 af = *(const short8*)(hb + lm * LDP + kst * 32 + lq * 8);
      #pragma unroll
      for (int p = 0; p < 4; ++p)
        acc[p] = __builtin_amdgcn_mfma_f32_16x16x32_bf16(af, bhhf[p][kst], acc[p], 0, 0, 0);
    }
    #pragma unroll
    for (int ks = 0; ks < 3; ++ks) {
      short8 af;
      #pragma unroll
      for (int jj = 0; jj < 8; ++jj) {
        const int kk = ks * 32 + lq * 8 + jj;
        short v = ((kk == xv) || (kk == 64 + av)) ? (short)0x3F80 : (short)0;
        if (kk == 80) v = (short)rwb;
        if (kk == 81) v = (short)dnb;
        af[jj] = v;
      }
      #pragma unroll
      for (int p = 0; p < 4; ++p)
        acc[p] = __builtin_amdgcn_mfma_f32_16x16x32_bf16(af, bihf[p][ks], acc[p], 0, 0, 0);
    }
    short* hw = hbuf[t & 1];
    #pragma unroll
    for (int r = 0; r < 4; ++r) {
      const float iv = acc[0][r] + bs[0], fv = acc[1][r] + bs[1];
      const float gv = acc[2][r] + bs[2], ov = acc[3][r] + bs[3];
      const float c = sigf(fv) * cst[r] + sigf(iv) * tanhf_fast(gv);
      cst[r] = c;
      const float hn = sigf(ov) * tanhf_fast(c);
      hlast[r] = hn;
      const int m = lq * 4 + r;
      out[((size_t)(b0 + m) * Tt + t) * Hh + j] = hn;
      hw[m * LDP + j] = (short)bf16u(hn);
    }
    __syncthreads();
  }
  const size_t base = (size_t)Bb * Tt * Hh;
  #pragma unroll
  for (int r = 0; r < 4; ++r) {
    const int m = lq * 4 + r;
    out[base + (size_t)(b0 + m) * (2 * Hh) + j]      = hlast[r];
    out[base + (size_t)(b0 + m) * (2 * Hh) + Hh + j] = cst[r];
  }
}

}  // namespace

extern "C" void kernel_launch(void* const* d_in, const int* in_sizes, int n_in,
                              void* d_out, int out_size, void* d_ws, size_t ws_size,
                              hipStream_t stream) {
  const int*   xs     = (const int*)  d_in[0];
  const float* hidden = (const float*)d_in[1];
  const int*   pa     = (const int*)  d_in[2];
  const float* prw    = (const float*)d_in[3];
  const float* pdn    = (const float*)d_in[4];
  const float* Wih    = (const float*)d_in[5];
  const float* Whh    = (const float*)d_in[6];
  const float* bih    = (const float*)d_in[7];
  const float* bhh    = (const float*)d_in[8];
  float* out = (float*)d_out;

  if (ws_size >= WS_NEED) {
    unsigned char* ws = (unsigned char*)d_ws;
    const int prepN = (1024 * 1024 + Bb * Tt + 2 * 16 * 8 * 64 + 255) / 256;
    prep_kernel<<<dim3(prepN), dim3(256), 0, stream>>>(xs, pa, prw, pdn, Wih, Whh, ws);
    lstm_rec<<<dim3(32), dim3(1024), 0, stream>>>(hidden, Whh, Wih, bih, bhh, ws, out);
  } else {
    lstm_fused<<<dim3(8), dim3(1024), 0, stream>>>(
        xs, hidden, pa, prw, pdn, Wih, Whh, bih, bhh, out);
  }
}